// Round 8
// baseline (745.674 us; speedup 1.0000x reference)
//
#include <hip/hip_runtime.h>
#include <hip/hip_bf16.h>

// ---------------- problem constants (fixed by setup_inputs) ----------------
#define NUM_B   16
#define DIM     512
#define TT      1500
#define NROWS   (NUM_B * TT)              // 24000
#define NCODES  4096
#define ROW_TILES ((NROWS + 127) / 128)   // 188
#define NROWS_PAD (ROW_TILES * 128)       // 24064
#define NSLICE  8                         // partial cd slices (atomic decontention)
#define SHIFTC  30.0f                     // exp shift: exp(SHIFT-d), cancels in softmax
#define NBLKX   (NCODES / 128)            // 32 col tiles
#define NBLK    (NBLKX * ROW_TILES)       // 6016 gemm blocks
#define TBLKS   (NUM_B * 47)              // 752 transpose blocks (47 t-tiles of 32)
#define CBLKS   (NCODES / 4)              // 1024 cb blocks
#define NZERO   (NROWS_PAD + NSLICE * NCODES + ROW_TILES + 1)   // Sg+cdp+rowcnt+done

typedef __bf16 bf16x8 __attribute__((ext_vector_type(8)));
typedef float  floatx4 __attribute__((ext_vector_type(4)));
typedef unsigned short ushortx8 __attribute__((ext_vector_type(8)));

// async global->LDS, 16B per lane; dest = wave-uniform base + lane*16
__device__ __forceinline__ void glds16(const void* g, void* l) {
    __builtin_amdgcn_global_load_lds(
        (__attribute__((address_space(1))) void*)(void*)g,
        (__attribute__((address_space(3))) void*)l, 16, 0, 0);
}

// ---------------- prep: transpose + z2 (no atomics) + cb + ws zeroing ----------
// id < TBLKS: transpose block (b, t0): full-D 32t x 512d tile, LDS stride 513
//   (513%32==1 -> phase-1 writes and phase-2 reads both 2-way = free).
// id >= TBLKS: cb conversion block + zero Sg/cdp/rowcnt/blockdone.
__global__ __launch_bounds__(256) void k_prep(
    const float* __restrict__ sf, const float* __restrict__ cb,
    unsigned short* __restrict__ zbf, unsigned short* __restrict__ cbbf,
    float* __restrict__ z2, float* __restrict__ c2, float* __restrict__ zero0) {
    int id = blockIdx.x, tid = threadIdx.x;
    if (id < TBLKS) {
        __shared__ float tile[32][513];
        int b = id / 47, t0 = (id % 47) * 32;
        int tl = tid & 31, dg = tid >> 5;
        int t = t0 + tl;
        if (t < TT) {
            const float* src = sf + (size_t)b * DIM * TT + t;
#pragma unroll 8
            for (int k = 0; k < 64; ++k) {
                int d = dg * 64 + k;
                tile[tl][d] = src[(size_t)d * TT];
            }
        }
        __syncthreads();
        int tr = tid >> 3, dgr = tid & 7;
        int tg = t0 + tr;
        float ssq = 0.f;
        if (tg < TT) {
            unsigned short* dst = zbf + (size_t)(b * TT + tg) * DIM;
#pragma unroll
            for (int seg = 0; seg < 8; ++seg) {
                int d0 = seg * 64 + dgr * 8;
                unsigned int h[8];
#pragma unroll
                for (int i2 = 0; i2 < 8; ++i2) {
                    __hip_bfloat16 hb = __float2bfloat16(tile[tr][d0 + i2]);
                    h[i2] = __builtin_bit_cast(unsigned short, hb);
                    float vb = __bfloat162float(hb);
                    ssq += vb * vb;
                }
                uint4 o;
                o.x = h[0] | (h[1] << 16); o.y = h[2] | (h[3] << 16);
                o.z = h[4] | (h[5] << 16); o.w = h[6] | (h[7] << 16);
                *(uint4*)(dst + d0) = o;
            }
        }
        // reduce over the 8 lanes sharing tr (lane bits 0..2)
        ssq += __shfl_xor(ssq, 1); ssq += __shfl_xor(ssq, 2); ssq += __shfl_xor(ssq, 4);
        if (dgr == 0 && tg < TT) z2[b * TT + tg] = ssq;
    } else {
        int ci = id - TBLKS;
        int gid = ci * 256 + tid;
        if (gid < NZERO) zero0[gid] = 0.f;
        int k = ci * 4 + (tid >> 6);
        int lane = tid & 63;
        const float4* src = (const float4*)(cb + (size_t)k * DIM + lane * 8);
        float4 a = src[0], b2 = src[1];
        float vals[8] = {a.x, a.y, a.z, a.w, b2.x, b2.y, b2.z, b2.w};
        float s = 0.f;
        unsigned int h[8];
#pragma unroll
        for (int i = 0; i < 8; ++i) {
            __hip_bfloat16 hb = __float2bfloat16(vals[i]);
            h[i] = __builtin_bit_cast(unsigned short, hb);
            float vb = __bfloat162float(hb);
            s += vb * vb;
        }
        uint4 o;
        o.x = h[0] | (h[1] << 16); o.y = h[2] | (h[3] << 16);
        o.z = h[4] | (h[5] << 16); o.w = h[6] | (h[7] << 16);
        *(uint4*)(cbbf + (size_t)k * DIM + lane * 8) = o;
#pragma unroll
        for (int off = 32; off >= 1; off >>= 1) s += __shfl_down(s, off);
        if (lane == 0) c2[k] = s;
    }
}

// ---------------- fused pass: GEMM + exp + S + E, elected scan, elected final ----
__global__ __launch_bounds__(256, 2) void k_gemm1(
    const unsigned short* __restrict__ zbf, const unsigned short* __restrict__ cbbf,
    const float* __restrict__ z2, const float* __restrict__ c2,
    const int* __restrict__ lengths, const int* __restrict__ stride_p,
    float* __restrict__ Sg, unsigned short* __restrict__ Eg,
    float* __restrict__ cdp, int* __restrict__ rowcnt, int* __restrict__ blockdone,
    float* __restrict__ out) {
    __shared__ unsigned short As[128 * 64];
    __shared__ unsigned short Bs[128 * 64];
    __shared__ float z2s[128], c2s[128], rsS[128];
    __shared__ unsigned char vldp[128];
    __shared__ int s_any, sh_e;
    __shared__ float red[4], tot_s;
    int tid = threadIdx.x;
    int r0 = blockIdx.y * 128, c0 = blockIdx.x * 128;
    if (tid == 0) s_any = 0;
    __syncthreads();
    if (tid < 128) {
        int n = r0 + tid;
        int valid = 0;
        if (n < NROWS) {
            int b = n / TT, t = n - b * TT;
            int stride = stride_p[0];
            int nv = lengths[b] / stride;
            if (nv > TT) nv = TT;
            valid = (t < nv);
        }
        if (valid) atomicOr(&s_any, 1);
        vldp[tid] = (unsigned char)valid;
        z2s[tid] = z2[r0 + tid];
        c2s[tid] = c2[c0 + tid];
    }
    __syncthreads();
    if (s_any) {
        int wave = tid >> 6, lane = tid & 63;
        int l15 = lane & 15, l4 = lane >> 4;
        int wr = (wave >> 1) * 64, wc = (wave & 1) * 64;

        int srow = lane >> 3;
        int scg = (lane & 7) ^ srow;
        const unsigned short* ag = zbf + (size_t)(r0 + wave * 32 + srow) * DIM + scg * 8;
        const unsigned short* bg = cbbf + (size_t)(c0 + wave * 32 + srow) * DIM + scg * 8;
        unsigned short* al = As + (wave * 32) * 64;
        unsigned short* bl = Bs + (wave * 32) * 64;

        floatx4 acc[4][4];
        const floatx4 zero = {0.f, 0.f, 0.f, 0.f};
#pragma unroll
        for (int i = 0; i < 4; ++i)
#pragma unroll
            for (int j = 0; j < 4; ++j) acc[i][j] = zero;

        int sw = l15 & 7;

        for (int kc = 0; kc < 8; ++kc) {
#pragma unroll
            for (int q = 0; q < 4; ++q) {
                glds16(ag + (size_t)q * 8 * DIM + kc * 64, al + q * 8 * 64);
                glds16(bg + (size_t)q * 8 * DIM + kc * 64, bl + q * 8 * 64);
            }
            __syncthreads();
#pragma unroll
            for (int ks = 0; ks < 64; ks += 32) {
                int g = (ks >> 3) + l4;
                int pcg = g ^ sw;
                bf16x8 av[4], bv[4];
#pragma unroll
                for (int i = 0; i < 4; ++i)
                    av[i] = __builtin_bit_cast(bf16x8,
                        *(const ushortx8*)&As[(wr + 16 * i + l15) * 64 + pcg * 8]);
#pragma unroll
                for (int j = 0; j < 4; ++j)
                    bv[j] = __builtin_bit_cast(bf16x8,
                        *(const ushortx8*)&Bs[(wc + 16 * j + l15) * 64 + pcg * 8]);
#pragma unroll
                for (int i = 0; i < 4; ++i)
#pragma unroll
                    for (int j = 0; j < 4; ++j)
                        acc[i][j] = __builtin_amdgcn_mfma_f32_16x16x32_bf16(av[i], bv[j], acc[i][j], 0, 0, 0);
            }
            __syncthreads();
        }

        // epilogue (R3-proven): e = exp(SHIFT - sqrt(z2+c2-2*dot)); S; E[n][k]
        // C/D layout (m89-verified): col = lane&15, row = (lane>>4)*4 + reg
#pragma unroll
        for (int i = 0; i < 4; ++i) {
#pragma unroll
            for (int r = 0; r < 4; ++r) {
                int rl = wr + 16 * i + 4 * l4 + r;
                bool rv = vldp[rl] != 0;
                float z2v = z2s[rl];
                float s = 0.f;
                unsigned short* Ep = Eg + (size_t)(r0 + rl) * NCODES + c0 + wc + l15;
#pragma unroll
                for (int j = 0; j < 4; ++j) {
                    int cl = wc + 16 * j + l15;
                    float d2 = z2v + c2s[cl] - 2.0f * acc[i][j][r];
                    float d = sqrtf(fmaxf(d2, 1e-12f));
                    float e = __expf(SHIFTC - d);
                    s += e;
                    if (rv) Ep[16 * j] = __builtin_bit_cast(unsigned short, __float2bfloat16(e));
                }
                s += __shfl_xor(s, 1); s += __shfl_xor(s, 2);
                s += __shfl_xor(s, 4); s += __shfl_xor(s, 8);
                if (l15 == 0 && rv) atomicAdd(&Sg[r0 + rl], s);
            }
        }

        // ---- elected scan: last col-block of this row-tile sums E/S into cdp ----
        __threadfence();
        __syncthreads();
        if (tid == 0) sh_e = (atomicAdd(&rowcnt[blockIdx.y], 1) == NBLKX - 1);
        __syncthreads();
        if (sh_e) {
            if (tid < 128) rsS[tid] = vldp[tid] ? 1.0f / Sg[r0 + tid] : 0.0f;
            __syncthreads();
            float* outp = cdp + (size_t)(blockIdx.y & (NSLICE - 1)) * NCODES;
#pragma unroll
            for (int half = 0; half < 2; ++half) {
                int col0 = half * 2048 + tid * 8;
                float a[8] = {0.f, 0.f, 0.f, 0.f, 0.f, 0.f, 0.f, 0.f};
                for (int nn = 0; nn < 128; ++nn) {
                    float rn = rsS[nn];
                    if (rn == 0.f) continue;
                    uint4 v = *(const uint4*)(Eg + (size_t)(r0 + nn) * NCODES + col0);
                    unsigned int u[4] = {v.x, v.y, v.z, v.w};
#pragma unroll
                    for (int q = 0; q < 4; ++q) {
                        a[2 * q]     += rn * __builtin_bit_cast(float, u[q] << 16);
                        a[2 * q + 1] += rn * __builtin_bit_cast(float, u[q] & 0xffff0000u);
                    }
                }
#pragma unroll
                for (int q = 0; q < 8; ++q) atomicAdd(&outp[col0 + q], a[q]);
            }
            __threadfence();
        }
    }
    // ---- all blocks: elected final (entropy) when every block is done ----
    __syncthreads();
    if (tid == 0) sh_e = (atomicAdd(blockdone, 1) == NBLK - 1);
    __syncthreads();
    if (sh_e) {
        float vloc[16];
        float tsum = 0.f;
#pragma unroll
        for (int q = 0; q < 16; ++q) {
            int i = q * 256 + tid;
            float v = 0.f;
#pragma unroll
            for (int s = 0; s < NSLICE; ++s) v += cdp[(size_t)s * NCODES + i];
            vloc[q] = v;
            tsum += v;
        }
#pragma unroll
        for (int off = 32; off >= 1; off >>= 1) tsum += __shfl_down(tsum, off);
        if ((tid & 63) == 0) red[tid >> 6] = tsum;
        __syncthreads();
        if (tid == 0) tot_s = red[0] + red[1] + red[2] + red[3];
        __syncthreads();
        float inv = 1.0f / (tot_s + 1e-8f);
        float e = 0.f;
#pragma unroll
        for (int q = 0; q < 16; ++q) {
            float p = vloc[q] * inv;
            e += p * __logf(p + 1e-8f);
        }
#pragma unroll
        for (int off = 32; off >= 1; off >>= 1) e += __shfl_down(e, off);
        if ((tid & 63) == 0) red[tid >> 6] = e;
        __syncthreads();
        if (tid == 0) {
            float ee = red[0] + red[1] + red[2] + red[3];
            out[0] = 1.0f - (-ee) / __logf((float)NCODES);
        }
    }
}

// ---------------- fallback (small ws): two-pass GEMM (writes cdp slice 0) -------
template <int PASS>
__global__ __launch_bounds__(256, 2) void k_gemm(
    const unsigned short* __restrict__ zbf, const unsigned short* __restrict__ cbbf,
    const float* __restrict__ z2, const float* __restrict__ c2,
    const int* __restrict__ lengths, const int* __restrict__ stride_p,
    float* __restrict__ Sg, float* __restrict__ cd) {
    __shared__ unsigned short As[128 * 64];
    __shared__ unsigned short Bs[128 * 64];
    __shared__ float z2s[128], c2s[128], rs[128];
    __shared__ int s_any;
    int tid = threadIdx.x;
    int r0 = blockIdx.y * 128, c0 = blockIdx.x * 128;
    if (tid == 0) s_any = 0;
    __syncthreads();
    if (tid < 128) {
        int n = r0 + tid;
        int valid = 0;
        if (n < NROWS) {
            int b = n / TT, t = n - b * TT;
            int stride = stride_p[0];
            int nv = lengths[b] / stride;
            if (nv > TT) nv = TT;
            valid = (t < nv);
        }
        if (valid) atomicOr(&s_any, 1);
        z2s[tid] = z2[r0 + tid];
        c2s[tid] = c2[c0 + tid];
        if (PASS == 2) rs[tid] = valid ? (1.0f / Sg[r0 + tid]) : 0.0f;
    }
    __syncthreads();
    if (!s_any) return;

    int wave = tid >> 6, lane = tid & 63;
    int l15 = lane & 15, l4 = lane >> 4;
    int wr = (wave >> 1) * 64, wc = (wave & 1) * 64;
    int srow = lane >> 3;
    int scg = (lane & 7) ^ srow;
    const unsigned short* ag = zbf + (size_t)(r0 + wave * 32 + srow) * DIM + scg * 8;
    const unsigned short* bg = cbbf + (size_t)(c0 + wave * 32 + srow) * DIM + scg * 8;
    unsigned short* al = As + (wave * 32) * 64;
    unsigned short* bl = Bs + (wave * 32) * 64;

    floatx4 acc[4][4];
    const floatx4 zero = {0.f, 0.f, 0.f, 0.f};
#pragma unroll
    for (int i = 0; i < 4; ++i)
#pragma unroll
        for (int j = 0; j < 4; ++j) acc[i][j] = zero;
    int sw = l15 & 7;
    for (int kc = 0; kc < 8; ++kc) {
#pragma unroll
        for (int q = 0; q < 4; ++q) {
            glds16(ag + (size_t)q * 8 * DIM + kc * 64, al + q * 8 * 64);
            glds16(bg + (size_t)q * 8 * DIM + kc * 64, bl + q * 8 * 64);
        }
        __syncthreads();
#pragma unroll
        for (int ks = 0; ks < 64; ks += 32) {
            int g = (ks >> 3) + l4;
            int pcg = g ^ sw;
            bf16x8 av[4], bv[4];
#pragma unroll
            for (int i = 0; i < 4; ++i)
                av[i] = __builtin_bit_cast(bf16x8, *(const ushortx8*)&As[(wr + 16 * i + l15) * 64 + pcg * 8]);
#pragma unroll
            for (int j = 0; j < 4; ++j)
                bv[j] = __builtin_bit_cast(bf16x8, *(const ushortx8*)&Bs[(wc + 16 * j + l15) * 64 + pcg * 8]);
#pragma unroll
            for (int i = 0; i < 4; ++i)
#pragma unroll
                for (int j = 0; j < 4; ++j)
                    acc[i][j] = __builtin_amdgcn_mfma_f32_16x16x32_bf16(av[i], bv[j], acc[i][j], 0, 0, 0);
        }
        __syncthreads();
    }
    if (PASS == 1) {
#pragma unroll
        for (int i = 0; i < 4; ++i) {
#pragma unroll
            for (int r = 0; r < 4; ++r) {
                int rl = wr + 16 * i + 4 * l4 + r;
                float z2v = z2s[rl];
                float s = 0.f;
#pragma unroll
                for (int j = 0; j < 4; ++j) {
                    int cl = wc + 16 * j + l15;
                    float d2 = z2v + c2s[cl] - 2.0f * acc[i][j][r];
                    float d = sqrtf(fmaxf(d2, 1e-12f));
                    s += __expf(SHIFTC - d);
                }
                s += __shfl_xor(s, 1); s += __shfl_xor(s, 2);
                s += __shfl_xor(s, 4); s += __shfl_xor(s, 8);
                if (l15 == 0) atomicAdd(&Sg[r0 + rl], s);
            }
        }
    } else {
#pragma unroll
        for (int j = 0; j < 4; ++j) {
            int cl = wc + 16 * j + l15;
            float c2v = c2s[cl];
            float cs = 0.f;
#pragma unroll
            for (int i = 0; i < 4; ++i) {
#pragma unroll
                for (int r = 0; r < 4; ++r) {
                    int rl = wr + 16 * i + 4 * l4 + r;
                    float d2 = z2s[rl] + c2v - 2.0f * acc[i][j][r];
                    float d = sqrtf(fmaxf(d2, 1e-12f));
                    cs += __expf(SHIFTC - d) * rs[rl];
                }
            }
            cs += __shfl_xor(cs, 16); cs += __shfl_xor(cs, 32);
            if (l4 == 0) atomicAdd(&cd[c0 + cl], cs);
        }
    }
}

// ---------------- fallback finalize ----------------
__global__ __launch_bounds__(1024) void k_final(const float* __restrict__ cdp,
                                                float* __restrict__ out) {
    __shared__ float red[16];
    __shared__ float tot_s;
    int tid = threadIdx.x, lane = tid & 63, wave = tid >> 6;
    float vloc[4];
    float t = 0.f;
#pragma unroll
    for (int q = 0; q < 4; ++q) {
        int i = tid + q * 1024;
        float v = 0.f;
#pragma unroll
        for (int s = 0; s < NSLICE; ++s) v += cdp[(size_t)s * NCODES + i];
        vloc[q] = v;
        t += v;
    }
#pragma unroll
    for (int off = 32; off >= 1; off >>= 1) t += __shfl_down(t, off);
    if (lane == 0) red[wave] = t;
    __syncthreads();
    if (tid == 0) {
        float tt = 0.f;
#pragma unroll
        for (int w = 0; w < 16; ++w) tt += red[w];
        tot_s = tt;
    }
    __syncthreads();
    float inv = 1.0f / (tot_s + 1e-8f);
    float e = 0.f;
#pragma unroll
    for (int q = 0; q < 4; ++q) {
        float p = vloc[q] * inv;
        e += p * __logf(p + 1e-8f);
    }
#pragma unroll
    for (int off = 32; off >= 1; off >>= 1) e += __shfl_down(e, off);
    if (lane == 0) red[wave] = e;
    __syncthreads();
    if (tid == 0) {
        float ee = 0.f;
#pragma unroll
        for (int w = 0; w < 16; ++w) ee += red[w];
        out[0] = 1.0f - (-ee) / __logf((float)NCODES);
    }
}

// ---------------- launcher ----------------
extern "C" void kernel_launch(void* const* d_in, const int* in_sizes, int n_in,
                              void* d_out, int out_size, void* d_ws, size_t ws_size,
                              hipStream_t stream) {
    const float* sf = (const float*)d_in[0];
    const float* cb = (const float*)d_in[1];
    const int* lengths = (const int*)d_in[2];
    const int* stride_p = (const int*)d_in[3];

    float* wsf = (float*)d_ws;
    float* Sg = wsf;                                     // NROWS_PAD
    float* cdp = Sg + NROWS_PAD;                         // NSLICE*NCODES
    int* rowcnt = (int*)(cdp + (size_t)NSLICE * NCODES); // ROW_TILES
    int* blockdone = rowcnt + ROW_TILES;                 // 1
    const size_t OFF_Z2 = NZERO;
    const size_t OFF_C2 = OFF_Z2 + NROWS_PAD;
    const size_t OFF_ZB = (OFF_C2 + NCODES + 3) & ~(size_t)3;  // 16B-align bf16 region
    float* z2 = wsf + OFF_Z2;
    float* c2 = wsf + OFF_C2;
    unsigned short* zbf = (unsigned short*)(wsf + OFF_ZB);     // NROWS_PAD*DIM bf16
    unsigned short* cbbf = zbf + (size_t)NROWS_PAD * DIM;      // NCODES*DIM bf16
    unsigned short* Eg = cbbf + (size_t)NCODES * DIM;          // NROWS_PAD*NCODES bf16

    size_t need = OFF_ZB * 4
                + ((size_t)NROWS_PAD * DIM + (size_t)NCODES * DIM
                 + (size_t)NROWS_PAD * NCODES) * 2;

    k_prep<<<dim3(TBLKS + CBLKS), 256, 0, stream>>>(sf, cb, zbf, cbbf, z2, c2, Sg);
    if (ws_size >= need) {
        k_gemm1<<<dim3(NBLKX, ROW_TILES), 256, 0, stream>>>(
            zbf, cbbf, z2, c2, lengths, stride_p, Sg, Eg, cdp, rowcnt, blockdone,
            (float*)d_out);
    } else {
        k_gemm<1><<<dim3(NBLKX, ROW_TILES), 256, 0, stream>>>(zbf, cbbf, z2, c2, lengths, stride_p, Sg, cdp);
        k_gemm<2><<<dim3(NBLKX, ROW_TILES), 256, 0, stream>>>(zbf, cbbf, z2, c2, lengths, stride_p, Sg, cdp);
        k_final<<<1, 1024, 0, stream>>>(cdp, (float*)d_out);
    }
}

// Round 9
// 370.858 us; speedup vs baseline: 2.0107x; 2.0107x over previous
//
#include <hip/hip_runtime.h>
#include <hip/hip_bf16.h>

// ---------------- problem constants (fixed by setup_inputs) ----------------
#define NUM_B   16
#define DIM     512
#define TT      1500
#define NROWS   (NUM_B * TT)              // 24000
#define NCODES  4096
#define ROW_TILES ((NROWS + 127) / 128)   // 188
#define NROWS_PAD (ROW_TILES * 128)       // 24064
#define NSLICE  8                         // partial cd slices (atomic decontention)
#define SHIFTC  30.0f                     // exp shift: exp(SHIFT-d), cancels in softmax
#define NBLKX   (NCODES / 128)            // 32 col tiles
#define TBLKS   (NUM_B * 47)              // 752 transpose blocks (47 t-tiles of 32)
#define CBLKS   (NCODES / 4)              // 1024 cb blocks
#define NSCAN   (2 * (NROWS_PAD / 32))    // 1504 scan blocks
#define NZERO   (NROWS_PAD + NSLICE * NCODES + 1)   // Sg + cdp + scandone

typedef __bf16 bf16x8 __attribute__((ext_vector_type(8)));
typedef float  floatx4 __attribute__((ext_vector_type(4)));
typedef unsigned short ushortx8 __attribute__((ext_vector_type(8)));

// async global->LDS, 16B per lane; dest = wave-uniform base + lane*16
__device__ __forceinline__ void glds16(const void* g, void* l) {
    __builtin_amdgcn_global_load_lds(
        (__attribute__((address_space(1))) void*)(void*)g,
        (__attribute__((address_space(3))) void*)l, 16, 0, 0);
}

// ---------------- prep: transpose + z2 (no atomics) + cb + ws zeroing ----------
// id < TBLKS: transpose block (b, t0): full-D 32t x 512d tile, LDS stride 513
//   (513%32==1 -> phase-1 writes and phase-2 reads both 2-way = free).
// id >= TBLKS: cb conversion block + zero Sg/cdp/scandone.
__global__ __launch_bounds__(256) void k_prep(
    const float* __restrict__ sf, const float* __restrict__ cb,
    unsigned short* __restrict__ zbf, unsigned short* __restrict__ cbbf,
    float* __restrict__ z2, float* __restrict__ c2, float* __restrict__ zero0) {
    int id = blockIdx.x, tid = threadIdx.x;
    if (id < TBLKS) {
        __shared__ float tile[32][513];
        int b = id / 47, t0 = (id % 47) * 32;
        int tl = tid & 31, dg = tid >> 5;
        int t = t0 + tl;
        if (t < TT) {
            const float* src = sf + (size_t)b * DIM * TT + t;
#pragma unroll 8
            for (int k = 0; k < 64; ++k) {
                int d = dg * 64 + k;
                tile[tl][d] = src[(size_t)d * TT];
            }
        }
        __syncthreads();
        int tr = tid >> 3, dgr = tid & 7;
        int tg = t0 + tr;
        float ssq = 0.f;
        if (tg < TT) {
            unsigned short* dst = zbf + (size_t)(b * TT + tg) * DIM;
#pragma unroll
            for (int seg = 0; seg < 8; ++seg) {
                int d0 = seg * 64 + dgr * 8;
                unsigned int h[8];
#pragma unroll
                for (int i2 = 0; i2 < 8; ++i2) {
                    __hip_bfloat16 hb = __float2bfloat16(tile[tr][d0 + i2]);
                    h[i2] = __builtin_bit_cast(unsigned short, hb);
                    float vb = __bfloat162float(hb);
                    ssq += vb * vb;
                }
                uint4 o;
                o.x = h[0] | (h[1] << 16); o.y = h[2] | (h[3] << 16);
                o.z = h[4] | (h[5] << 16); o.w = h[6] | (h[7] << 16);
                *(uint4*)(dst + d0) = o;
            }
        }
        // reduce over the 8 lanes sharing tr (lane bits 0..2)
        ssq += __shfl_xor(ssq, 1); ssq += __shfl_xor(ssq, 2); ssq += __shfl_xor(ssq, 4);
        if (dgr == 0 && tg < TT) z2[b * TT + tg] = ssq;
    } else {
        int ci = id - TBLKS;
        int gid = ci * 256 + tid;
        if (gid < NZERO) zero0[gid] = 0.f;
        int k = ci * 4 + (tid >> 6);
        int lane = tid & 63;
        const float4* src = (const float4*)(cb + (size_t)k * DIM + lane * 8);
        float4 a = src[0], b2 = src[1];
        float vals[8] = {a.x, a.y, a.z, a.w, b2.x, b2.y, b2.z, b2.w};
        float s = 0.f;
        unsigned int h[8];
#pragma unroll
        for (int i = 0; i < 8; ++i) {
            __hip_bfloat16 hb = __float2bfloat16(vals[i]);
            h[i] = __builtin_bit_cast(unsigned short, hb);
            float vb = __bfloat162float(hb);
            s += vb * vb;
        }
        uint4 o;
        o.x = h[0] | (h[1] << 16); o.y = h[2] | (h[3] << 16);
        o.z = h[4] | (h[5] << 16); o.w = h[6] | (h[7] << 16);
        *(uint4*)(cbbf + (size_t)k * DIM + lane * 8) = o;
#pragma unroll
        for (int off = 32; off >= 1; off >>= 1) s += __shfl_down(s, off);
        if (lane == 0) c2[k] = s;
    }
}

// ---------------- pass 1: GEMM + exp; accumulate S, store E bf16 (exact R7) -----
__global__ __launch_bounds__(256, 2) void k_gemm1(
    const unsigned short* __restrict__ zbf, const unsigned short* __restrict__ cbbf,
    const float* __restrict__ z2, const float* __restrict__ c2,
    const int* __restrict__ lengths, const int* __restrict__ stride_p,
    float* __restrict__ Sg, unsigned short* __restrict__ Eg) {
    __shared__ unsigned short As[128 * 64];
    __shared__ unsigned short Bs[128 * 64];
    __shared__ float z2s[128], c2s[128];
    __shared__ unsigned char vldp[128];
    __shared__ int s_any;
    int tid = threadIdx.x;
    int r0 = blockIdx.y * 128, c0 = blockIdx.x * 128;
    if (tid == 0) s_any = 0;
    __syncthreads();
    if (tid < 128) {
        int n = r0 + tid;
        int valid = 0;
        if (n < NROWS) {
            int b = n / TT, t = n - b * TT;
            int stride = stride_p[0];
            int nv = lengths[b] / stride;
            if (nv > TT) nv = TT;
            valid = (t < nv);
        }
        if (valid) atomicOr(&s_any, 1);
        vldp[tid] = (unsigned char)valid;
        z2s[tid] = z2[r0 + tid];
        c2s[tid] = c2[c0 + tid];
    }
    __syncthreads();
    if (!s_any) return;   // fully-masked row tile: contributes nothing

    int wave = tid >> 6, lane = tid & 63;
    int l15 = lane & 15, l4 = lane >> 4;
    int wr = (wave >> 1) * 64, wc = (wave & 1) * 64;

    int srow = lane >> 3;
    int scg = (lane & 7) ^ srow;
    const unsigned short* ag = zbf + (size_t)(r0 + wave * 32 + srow) * DIM + scg * 8;
    const unsigned short* bg = cbbf + (size_t)(c0 + wave * 32 + srow) * DIM + scg * 8;
    unsigned short* al = As + (wave * 32) * 64;
    unsigned short* bl = Bs + (wave * 32) * 64;

    floatx4 acc[4][4];
    const floatx4 zero = {0.f, 0.f, 0.f, 0.f};
#pragma unroll
    for (int i = 0; i < 4; ++i)
#pragma unroll
        for (int j = 0; j < 4; ++j) acc[i][j] = zero;

    int sw = l15 & 7;

    for (int kc = 0; kc < 8; ++kc) {
#pragma unroll
        for (int q = 0; q < 4; ++q) {
            glds16(ag + (size_t)q * 8 * DIM + kc * 64, al + q * 8 * 64);
            glds16(bg + (size_t)q * 8 * DIM + kc * 64, bl + q * 8 * 64);
        }
        __syncthreads();
#pragma unroll
        for (int ks = 0; ks < 64; ks += 32) {
            int g = (ks >> 3) + l4;
            int pcg = g ^ sw;
            bf16x8 av[4], bv[4];
#pragma unroll
            for (int i = 0; i < 4; ++i)
                av[i] = __builtin_bit_cast(bf16x8,
                    *(const ushortx8*)&As[(wr + 16 * i + l15) * 64 + pcg * 8]);
#pragma unroll
            for (int j = 0; j < 4; ++j)
                bv[j] = __builtin_bit_cast(bf16x8,
                    *(const ushortx8*)&Bs[(wc + 16 * j + l15) * 64 + pcg * 8]);
#pragma unroll
            for (int i = 0; i < 4; ++i)
#pragma unroll
                for (int j = 0; j < 4; ++j)
                    acc[i][j] = __builtin_amdgcn_mfma_f32_16x16x32_bf16(av[i], bv[j], acc[i][j], 0, 0, 0);
        }
        __syncthreads();
    }

    // epilogue (exact R3): e = exp(SHIFT - sqrt(z2+c2-2*dot)); S += row-sum; E[n][k]
    // C/D layout (m89-verified): col = lane&15, row = (lane>>4)*4 + reg
#pragma unroll
    for (int i = 0; i < 4; ++i) {
#pragma unroll
        for (int r = 0; r < 4; ++r) {
            int rl = wr + 16 * i + 4 * l4 + r;
            bool rv = vldp[rl] != 0;
            float z2v = z2s[rl];
            float s = 0.f;
            unsigned short* Ep = Eg + (size_t)(r0 + rl) * NCODES + c0 + wc + l15;
#pragma unroll
            for (int j = 0; j < 4; ++j) {
                int cl = wc + 16 * j + l15;
                float d2 = z2v + c2s[cl] - 2.0f * acc[i][j][r];
                float d = sqrtf(fmaxf(d2, 1e-12f));
                float e = __expf(SHIFTC - d);
                s += e;
                if (rv) Ep[16 * j] = __builtin_bit_cast(unsigned short, __float2bfloat16(e));
            }
            s += __shfl_xor(s, 1); s += __shfl_xor(s, 2);
            s += __shfl_xor(s, 4); s += __shfl_xor(s, 8);
            if (l15 == 0 && rv) atomicAdd(&Sg[r0 + rl], s);
        }
    }
}

// ---------------- pass 2: scan + elected entropy finale ----------------
// R4-proven geometry: grid (2, 752); 32 rows x 2048 cols; 8 cols/thread;
// one contiguous uint4 per row-iter. Last-finishing block computes entropy.
__global__ __launch_bounds__(256) void k_scanfinal(
    const unsigned short* __restrict__ Eg, const float* __restrict__ Sg,
    const int* __restrict__ lengths, const int* __restrict__ stride_p,
    float* __restrict__ cdp, int* __restrict__ scandone, float* __restrict__ out) {
    __shared__ float rs[32];
    __shared__ int s_any, sh_e;
    __shared__ float red[4], tot_s;
    int tid = threadIdx.x;
    int r0 = blockIdx.y * 32;
    if (tid == 0) s_any = 0;
    __syncthreads();
    if (tid < 32) {
        int n = r0 + tid;
        int valid = 0;
        if (n < NROWS) {
            int b = n / TT, t = n - b * TT;
            int nv = lengths[b] / stride_p[0];
            if (nv > TT) nv = TT;
            valid = (t < nv);
        }
        if (valid) atomicOr(&s_any, 1);
        rs[tid] = valid ? 1.0f / Sg[n] : 0.0f;
    }
    __syncthreads();
    if (s_any) {
        int col0 = blockIdx.x * 2048 + tid * 8;
        float acc[8] = {0.f, 0.f, 0.f, 0.f, 0.f, 0.f, 0.f, 0.f};
        for (int nn = 0; nn < 32; ++nn) {
            float rn = rs[nn];
            if (rn == 0.f) continue;        // wave-uniform: prefix-mask rows skip
            uint4 v = *(const uint4*)(Eg + (size_t)(r0 + nn) * NCODES + col0);
            unsigned int u[4] = {v.x, v.y, v.z, v.w};
#pragma unroll
            for (int q = 0; q < 4; ++q) {
                acc[2 * q]     += rn * __builtin_bit_cast(float, u[q] << 16);
                acc[2 * q + 1] += rn * __builtin_bit_cast(float, u[q] & 0xffff0000u);
            }
        }
        float* outp = cdp + (size_t)(blockIdx.y & (NSLICE - 1)) * NCODES;
#pragma unroll
        for (int t = 0; t < 8; ++t) atomicAdd(&outp[col0 + t], acc[t]);
    }
    // election: last-finishing block computes the entropy
    __threadfence();
    __syncthreads();
    if (tid == 0) sh_e = (atomicAdd(scandone, 1) == NSCAN - 1);
    __syncthreads();
    if (sh_e) {
        float vloc[16];
        float tsum = 0.f;
#pragma unroll
        for (int q = 0; q < 16; ++q) {
            int i = q * 256 + tid;
            float v = 0.f;
#pragma unroll
            for (int s = 0; s < NSLICE; ++s)
                v += __hip_atomic_load(&cdp[(size_t)s * NCODES + i],
                                       __ATOMIC_RELAXED, __HIP_MEMORY_SCOPE_AGENT);
            vloc[q] = v;
            tsum += v;
        }
#pragma unroll
        for (int off = 32; off >= 1; off >>= 1) tsum += __shfl_down(tsum, off);
        if ((tid & 63) == 0) red[tid >> 6] = tsum;
        __syncthreads();
        if (tid == 0) tot_s = red[0] + red[1] + red[2] + red[3];
        __syncthreads();
        float inv = 1.0f / (tot_s + 1e-8f);
        float e = 0.f;
#pragma unroll
        for (int q = 0; q < 16; ++q) {
            float p = vloc[q] * inv;
            e += p * __logf(p + 1e-8f);
        }
#pragma unroll
        for (int off = 32; off >= 1; off >>= 1) e += __shfl_down(e, off);
        if ((tid & 63) == 0) red[tid >> 6] = e;
        __syncthreads();
        if (tid == 0) {
            float ee = red[0] + red[1] + red[2] + red[3];
            out[0] = 1.0f - (-ee) / __logf((float)NCODES);
        }
    }
}

// ---------------- fallback (small ws): two-pass GEMM (writes cdp slice 0) -------
template <int PASS>
__global__ __launch_bounds__(256, 2) void k_gemm(
    const unsigned short* __restrict__ zbf, const unsigned short* __restrict__ cbbf,
    const float* __restrict__ z2, const float* __restrict__ c2,
    const int* __restrict__ lengths, const int* __restrict__ stride_p,
    float* __restrict__ Sg, float* __restrict__ cd) {
    __shared__ unsigned short As[128 * 64];
    __shared__ unsigned short Bs[128 * 64];
    __shared__ float z2s[128], c2s[128], rs[128];
    __shared__ int s_any;
    int tid = threadIdx.x;
    int r0 = blockIdx.y * 128, c0 = blockIdx.x * 128;
    if (tid == 0) s_any = 0;
    __syncthreads();
    if (tid < 128) {
        int n = r0 + tid;
        int valid = 0;
        if (n < NROWS) {
            int b = n / TT, t = n - b * TT;
            int stride = stride_p[0];
            int nv = lengths[b] / stride;
            if (nv > TT) nv = TT;
            valid = (t < nv);
        }
        if (valid) atomicOr(&s_any, 1);
        z2s[tid] = z2[r0 + tid];
        c2s[tid] = c2[c0 + tid];
        if (PASS == 2) rs[tid] = valid ? (1.0f / Sg[r0 + tid]) : 0.0f;
    }
    __syncthreads();
    if (!s_any) return;

    int wave = tid >> 6, lane = tid & 63;
    int l15 = lane & 15, l4 = lane >> 4;
    int wr = (wave >> 1) * 64, wc = (wave & 1) * 64;
    int srow = lane >> 3;
    int scg = (lane & 7) ^ srow;
    const unsigned short* ag = zbf + (size_t)(r0 + wave * 32 + srow) * DIM + scg * 8;
    const unsigned short* bg = cbbf + (size_t)(c0 + wave * 32 + srow) * DIM + scg * 8;
    unsigned short* al = As + (wave * 32) * 64;
    unsigned short* bl = Bs + (wave * 32) * 64;

    floatx4 acc[4][4];
    const floatx4 zero = {0.f, 0.f, 0.f, 0.f};
#pragma unroll
    for (int i = 0; i < 4; ++i)
#pragma unroll
        for (int j = 0; j < 4; ++j) acc[i][j] = zero;
    int sw = l15 & 7;
    for (int kc = 0; kc < 8; ++kc) {
#pragma unroll
        for (int q = 0; q < 4; ++q) {
            glds16(ag + (size_t)q * 8 * DIM + kc * 64, al + q * 8 * 64);
            glds16(bg + (size_t)q * 8 * DIM + kc * 64, bl + q * 8 * 64);
        }
        __syncthreads();
#pragma unroll
        for (int ks = 0; ks < 64; ks += 32) {
            int g = (ks >> 3) + l4;
            int pcg = g ^ sw;
            bf16x8 av[4], bv[4];
#pragma unroll
            for (int i = 0; i < 4; ++i)
                av[i] = __builtin_bit_cast(bf16x8, *(const ushortx8*)&As[(wr + 16 * i + l15) * 64 + pcg * 8]);
#pragma unroll
            for (int j = 0; j < 4; ++j)
                bv[j] = __builtin_bit_cast(bf16x8, *(const ushortx8*)&Bs[(wc + 16 * j + l15) * 64 + pcg * 8]);
#pragma unroll
            for (int i = 0; i < 4; ++i)
#pragma unroll
                for (int j = 0; j < 4; ++j)
                    acc[i][j] = __builtin_amdgcn_mfma_f32_16x16x32_bf16(av[i], bv[j], acc[i][j], 0, 0, 0);
        }
        __syncthreads();
    }
    if (PASS == 1) {
#pragma unroll
        for (int i = 0; i < 4; ++i) {
#pragma unroll
            for (int r = 0; r < 4; ++r) {
                int rl = wr + 16 * i + 4 * l4 + r;
                float z2v = z2s[rl];
                float s = 0.f;
#pragma unroll
                for (int j = 0; j < 4; ++j) {
                    int cl = wc + 16 * j + l15;
                    float d2 = z2v + c2s[cl] - 2.0f * acc[i][j][r];
                    float d = sqrtf(fmaxf(d2, 1e-12f));
                    s += __expf(SHIFTC - d);
                }
                s += __shfl_xor(s, 1); s += __shfl_xor(s, 2);
                s += __shfl_xor(s, 4); s += __shfl_xor(s, 8);
                if (l15 == 0) atomicAdd(&Sg[r0 + rl], s);
            }
        }
    } else {
#pragma unroll
        for (int j = 0; j < 4; ++j) {
            int cl = wc + 16 * j + l15;
            float c2v = c2s[cl];
            float cs = 0.f;
#pragma unroll
            for (int i = 0; i < 4; ++i) {
#pragma unroll
                for (int r = 0; r < 4; ++r) {
                    int rl = wr + 16 * i + 4 * l4 + r;
                    float d2 = z2s[rl] + c2v - 2.0f * acc[i][j][r];
                    float d = sqrtf(fmaxf(d2, 1e-12f));
                    cs += __expf(SHIFTC - d) * rs[rl];
                }
            }
            cs += __shfl_xor(cs, 16); cs += __shfl_xor(cs, 32);
            if (l4 == 0) atomicAdd(&cd[c0 + cl], cs);
        }
    }
}

// ---------------- fallback finalize ----------------
__global__ __launch_bounds__(1024) void k_final(const float* __restrict__ cdp,
                                                float* __restrict__ out) {
    __shared__ float red[16];
    __shared__ float tot_s;
    int tid = threadIdx.x, lane = tid & 63, wave = tid >> 6;
    float vloc[4];
    float t = 0.f;
#pragma unroll
    for (int q = 0; q < 4; ++q) {
        int i = tid + q * 1024;
        float v = 0.f;
#pragma unroll
        for (int s = 0; s < NSLICE; ++s) v += cdp[(size_t)s * NCODES + i];
        vloc[q] = v;
        t += v;
    }
#pragma unroll
    for (int off = 32; off >= 1; off >>= 1) t += __shfl_down(t, off);
    if (lane == 0) red[wave] = t;
    __syncthreads();
    if (tid == 0) {
        float tt = 0.f;
#pragma unroll
        for (int w = 0; w < 16; ++w) tt += red[w];
        tot_s = tt;
    }
    __syncthreads();
    float inv = 1.0f / (tot_s + 1e-8f);
    float e = 0.f;
#pragma unroll
    for (int q = 0; q < 4; ++q) {
        float p = vloc[q] * inv;
        e += p * __logf(p + 1e-8f);
    }
#pragma unroll
    for (int off = 32; off >= 1; off >>= 1) e += __shfl_down(e, off);
    if (lane == 0) red[wave] = e;
    __syncthreads();
    if (tid == 0) {
        float ee = 0.f;
#pragma unroll
        for (int w = 0; w < 16; ++w) ee += red[w];
        out[0] = 1.0f - (-ee) / __logf((float)NCODES);
    }
}

// ---------------- launcher ----------------
extern "C" void kernel_launch(void* const* d_in, const int* in_sizes, int n_in,
                              void* d_out, int out_size, void* d_ws, size_t ws_size,
                              hipStream_t stream) {
    const float* sf = (const float*)d_in[0];
    const float* cb = (const float*)d_in[1];
    const int* lengths = (const int*)d_in[2];
    const int* stride_p = (const int*)d_in[3];

    float* wsf = (float*)d_ws;
    float* Sg = wsf;                                     // NROWS_PAD
    float* cdp = Sg + NROWS_PAD;                         // NSLICE*NCODES
    int* scandone = (int*)(cdp + (size_t)NSLICE * NCODES); // 1
    const size_t OFF_Z2 = NZERO;
    const size_t OFF_C2 = OFF_Z2 + NROWS_PAD;
    const size_t OFF_ZB = (OFF_C2 + NCODES + 3) & ~(size_t)3;  // 16B-align bf16 region
    float* z2 = wsf + OFF_Z2;
    float* c2 = wsf + OFF_C2;
    unsigned short* zbf = (unsigned short*)(wsf + OFF_ZB);     // NROWS_PAD*DIM bf16
    unsigned short* cbbf = zbf + (size_t)NROWS_PAD * DIM;      // NCODES*DIM bf16
    unsigned short* Eg = cbbf + (size_t)NCODES * DIM;          // NROWS_PAD*NCODES bf16

    size_t need = OFF_ZB * 4
                + ((size_t)NROWS_PAD * DIM + (size_t)NCODES * DIM
                 + (size_t)NROWS_PAD * NCODES) * 2;

    k_prep<<<dim3(TBLKS + CBLKS), 256, 0, stream>>>(sf, cb, zbf, cbbf, z2, c2, Sg);
    if (ws_size >= need) {
        k_gemm1<<<dim3(NBLKX, ROW_TILES), 256, 0, stream>>>(
            zbf, cbbf, z2, c2, lengths, stride_p, Sg, Eg);
        k_scanfinal<<<dim3(2, NROWS_PAD / 32), 256, 0, stream>>>(
            Eg, Sg, lengths, stride_p, cdp, scandone, (float*)d_out);
    } else {
        k_gemm<1><<<dim3(NBLKX, ROW_TILES), 256, 0, stream>>>(zbf, cbbf, z2, c2, lengths, stride_p, Sg, cdp);
        k_gemm<2><<<dim3(NBLKX, ROW_TILES), 256, 0, stream>>>(zbf, cbbf, z2, c2, lengths, stride_p, Sg, cdp);
        k_final<<<1, 1024, 0, stream>>>(cdp, (float*)d_out);
    }
}

// Round 10
// 228.747 us; speedup vs baseline: 3.2598x; 1.6213x over previous
//
#include <hip/hip_runtime.h>
#include <hip/hip_bf16.h>

// ---------------- problem constants (fixed by setup_inputs) ----------------
#define NUM_B   16
#define DIM     512
#define TT      1500
#define NROWS   (NUM_B * TT)              // 24000
#define NCODES  4096
#define ROW_TILES ((NROWS + 127) / 128)   // 188
#define NROWS_PAD (ROW_TILES * 128)       // 24064
#define NSLICE  8                         // partial cd slices (atomic decontention)
#define SHIFTC  30.0f                     // exp shift: exp(SHIFT-d), cancels in softmax
#define NBLKX   (NCODES / 128)            // 32 col tiles
#define TBLKS   (NUM_B * 47)              // 752 transpose blocks (47 t-tiles of 32)
#define CBLKS   (NCODES / 4)              // 1024 cb blocks
#define NZERO   (NROWS_PAD + NSLICE * NCODES)   // Sg + cdp

typedef __bf16 bf16x8 __attribute__((ext_vector_type(8)));
typedef float  floatx4 __attribute__((ext_vector_type(4)));
typedef unsigned short ushortx8 __attribute__((ext_vector_type(8)));

// async global->LDS, 16B per lane; dest = wave-uniform base + lane*16
__device__ __forceinline__ void glds16(const void* g, void* l) {
    __builtin_amdgcn_global_load_lds(
        (__attribute__((address_space(1))) void*)(void*)g,
        (__attribute__((address_space(3))) void*)l, 16, 0, 0);
}

// ---------------- prep: transpose + z2 (register-accum) + cb + ws zeroing -------
// id < TBLKS: transpose block (b, t0): 2 phases of 32t x 256d, LDS stride 257
//   (257%32==1 -> phase-1 writes and phase-2 reads both <=2-way = free).
//   z2 accumulated in registers across phases -> no atomics, no pre-zero.
// id >= TBLKS: cb conversion block + zero Sg/cdp.
__global__ __launch_bounds__(256) void k_prep(
    const float* __restrict__ sf, const float* __restrict__ cb,
    unsigned short* __restrict__ zbf, unsigned short* __restrict__ cbbf,
    float* __restrict__ z2, float* __restrict__ c2, float* __restrict__ zero0) {
    int id = blockIdx.x, tid = threadIdx.x;
    if (id < TBLKS) {
        __shared__ float tile[32][257];
        int b = id / 47, t0 = (id % 47) * 32;
        int tl = tid & 31, dg = tid >> 5;       // phase 1: t lane, d group (8x32)
        int tr = tid >> 3, dgr = tid & 7;       // phase 2: 8 lanes per t-row
        int tg = t0 + tr;
        float ssq = 0.f;
        unsigned short* dst = zbf + (size_t)(b * TT + tg) * DIM;
#pragma unroll
        for (int half = 0; half < 2; ++half) {
            int dbase = half * 256;
            if (half) __syncthreads();          // drain phase-2 reads of prev half
            int t = t0 + tl;
            if (t < TT) {
                const float* src = sf + (size_t)(b * DIM + dbase + dg * 32) * TT + t;
#pragma unroll
                for (int k = 0; k < 32; ++k)
                    tile[tl][dg * 32 + k] = src[(size_t)k * TT];
            }
            __syncthreads();
            if (tg < TT) {
#pragma unroll
                for (int seg = 0; seg < 4; ++seg) {
                    int d0 = seg * 64 + dgr * 8;
                    unsigned int h[8];
#pragma unroll
                    for (int i2 = 0; i2 < 8; ++i2) {
                        __hip_bfloat16 hb = __float2bfloat16(tile[tr][d0 + i2]);
                        h[i2] = __builtin_bit_cast(unsigned short, hb);
                        float vb = __bfloat162float(hb);
                        ssq += vb * vb;
                    }
                    uint4 o;
                    o.x = h[0] | (h[1] << 16); o.y = h[2] | (h[3] << 16);
                    o.z = h[4] | (h[5] << 16); o.w = h[6] | (h[7] << 16);
                    *(uint4*)(dst + dbase + d0) = o;
                }
            }
        }
        // reduce over the 8 lanes sharing tr (lane bits 0..2)
        ssq += __shfl_xor(ssq, 1); ssq += __shfl_xor(ssq, 2); ssq += __shfl_xor(ssq, 4);
        if (dgr == 0 && tg < TT) z2[b * TT + tg] = ssq;
    } else {
        int ci = id - TBLKS;
        int gid = ci * 256 + tid;
        if (gid < NZERO) zero0[gid] = 0.f;
        int k = ci * 4 + (tid >> 6);
        int lane = tid & 63;
        const float4* src = (const float4*)(cb + (size_t)k * DIM + lane * 8);
        float4 a = src[0], b2 = src[1];
        float vals[8] = {a.x, a.y, a.z, a.w, b2.x, b2.y, b2.z, b2.w};
        float s = 0.f;
        unsigned int h[8];
#pragma unroll
        for (int i = 0; i < 8; ++i) {
            __hip_bfloat16 hb = __float2bfloat16(vals[i]);
            h[i] = __builtin_bit_cast(unsigned short, hb);
            float vb = __bfloat162float(hb);
            s += vb * vb;
        }
        uint4 o;
        o.x = h[0] | (h[1] << 16); o.y = h[2] | (h[3] << 16);
        o.z = h[4] | (h[5] << 16); o.w = h[6] | (h[7] << 16);
        *(uint4*)(cbbf + (size_t)k * DIM + lane * 8) = o;
#pragma unroll
        for (int off = 32; off >= 1; off >>= 1) s += __shfl_down(s, off);
        if (lane == 0) c2[k] = s;
    }
}

// ---------------- pass 1: GEMM + exp; accumulate S, store E bf16 (exact R7) -----
__global__ __launch_bounds__(256, 2) void k_gemm1(
    const unsigned short* __restrict__ zbf, const unsigned short* __restrict__ cbbf,
    const float* __restrict__ z2, const float* __restrict__ c2,
    const int* __restrict__ lengths, const int* __restrict__ stride_p,
    float* __restrict__ Sg, unsigned short* __restrict__ Eg) {
    __shared__ unsigned short As[128 * 64];
    __shared__ unsigned short Bs[128 * 64];
    __shared__ float z2s[128], c2s[128];
    __shared__ unsigned char vldp[128];
    __shared__ int s_any;
    int tid = threadIdx.x;
    int r0 = blockIdx.y * 128, c0 = blockIdx.x * 128;
    if (tid == 0) s_any = 0;
    __syncthreads();
    if (tid < 128) {
        int n = r0 + tid;
        int valid = 0;
        if (n < NROWS) {
            int b = n / TT, t = n - b * TT;
            int stride = stride_p[0];
            int nv = lengths[b] / stride;
            if (nv > TT) nv = TT;
            valid = (t < nv);
        }
        if (valid) atomicOr(&s_any, 1);
        vldp[tid] = (unsigned char)valid;
        z2s[tid] = z2[r0 + tid];
        c2s[tid] = c2[c0 + tid];
    }
    __syncthreads();
    if (!s_any) return;   // fully-masked row tile: contributes nothing

    int wave = tid >> 6, lane = tid & 63;
    int l15 = lane & 15, l4 = lane >> 4;
    int wr = (wave >> 1) * 64, wc = (wave & 1) * 64;

    int srow = lane >> 3;
    int scg = (lane & 7) ^ srow;
    const unsigned short* ag = zbf + (size_t)(r0 + wave * 32 + srow) * DIM + scg * 8;
    const unsigned short* bg = cbbf + (size_t)(c0 + wave * 32 + srow) * DIM + scg * 8;
    unsigned short* al = As + (wave * 32) * 64;
    unsigned short* bl = Bs + (wave * 32) * 64;

    floatx4 acc[4][4];
    const floatx4 zero = {0.f, 0.f, 0.f, 0.f};
#pragma unroll
    for (int i = 0; i < 4; ++i)
#pragma unroll
        for (int j = 0; j < 4; ++j) acc[i][j] = zero;

    int sw = l15 & 7;

    for (int kc = 0; kc < 8; ++kc) {
#pragma unroll
        for (int q = 0; q < 4; ++q) {
            glds16(ag + (size_t)q * 8 * DIM + kc * 64, al + q * 8 * 64);
            glds16(bg + (size_t)q * 8 * DIM + kc * 64, bl + q * 8 * 64);
        }
        __syncthreads();
#pragma unroll
        for (int ks = 0; ks < 64; ks += 32) {
            int g = (ks >> 3) + l4;
            int pcg = g ^ sw;
            bf16x8 av[4], bv[4];
#pragma unroll
            for (int i = 0; i < 4; ++i)
                av[i] = __builtin_bit_cast(bf16x8,
                    *(const ushortx8*)&As[(wr + 16 * i + l15) * 64 + pcg * 8]);
#pragma unroll
            for (int j = 0; j < 4; ++j)
                bv[j] = __builtin_bit_cast(bf16x8,
                    *(const ushortx8*)&Bs[(wc + 16 * j + l15) * 64 + pcg * 8]);
#pragma unroll
            for (int i = 0; i < 4; ++i)
#pragma unroll
                for (int j = 0; j < 4; ++j)
                    acc[i][j] = __builtin_amdgcn_mfma_f32_16x16x32_bf16(av[i], bv[j], acc[i][j], 0, 0, 0);
        }
        __syncthreads();
    }

    // epilogue (exact R3): e = exp(SHIFT - sqrt(z2+c2-2*dot)); S += row-sum; E[n][k]
    // C/D layout (m89-verified): col = lane&15, row = (lane>>4)*4 + reg
#pragma unroll
    for (int i = 0; i < 4; ++i) {
#pragma unroll
        for (int r = 0; r < 4; ++r) {
            int rl = wr + 16 * i + 4 * l4 + r;
            bool rv = vldp[rl] != 0;
            float z2v = z2s[rl];
            float s = 0.f;
            unsigned short* Ep = Eg + (size_t)(r0 + rl) * NCODES + c0 + wc + l15;
#pragma unroll
            for (int j = 0; j < 4; ++j) {
                int cl = wc + 16 * j + l15;
                float d2 = z2v + c2s[cl] - 2.0f * acc[i][j][r];
                float d = sqrtf(fmaxf(d2, 1e-12f));
                float e = __expf(SHIFTC - d);
                s += e;
                if (rv) Ep[16 * j] = __builtin_bit_cast(unsigned short, __float2bfloat16(e));
            }
            s += __shfl_xor(s, 1); s += __shfl_xor(s, 2);
            s += __shfl_xor(s, 4); s += __shfl_xor(s, 8);
            if (l15 == 0 && rv) atomicAdd(&Sg[r0 + rl], s);
        }
    }
}

// ---------------- pass 2: memory-bound scan  cdp[slice][k] += E[n][k]/S[n] ------
// R4-proven geometry: grid (2, 752); 32 rows x 2048 cols; 8 cols/thread;
// one contiguous uint4 per row-iter. NO fences, NO election.
__global__ __launch_bounds__(256) void k_scan(
    const unsigned short* __restrict__ Eg, const float* __restrict__ Sg,
    const int* __restrict__ lengths, const int* __restrict__ stride_p,
    float* __restrict__ cdp) {
    __shared__ float rs[32];
    __shared__ int s_any;
    int tid = threadIdx.x;
    int r0 = blockIdx.y * 32;
    if (tid == 0) s_any = 0;
    __syncthreads();
    if (tid < 32) {
        int n = r0 + tid;
        int valid = 0;
        if (n < NROWS) {
            int b = n / TT, t = n - b * TT;
            int nv = lengths[b] / stride_p[0];
            if (nv > TT) nv = TT;
            valid = (t < nv);
        }
        if (valid) atomicOr(&s_any, 1);
        rs[tid] = valid ? 1.0f / Sg[n] : 0.0f;
    }
    __syncthreads();
    if (!s_any) return;

    int col0 = blockIdx.x * 2048 + tid * 8;
    float acc[8] = {0.f, 0.f, 0.f, 0.f, 0.f, 0.f, 0.f, 0.f};
    for (int nn = 0; nn < 32; ++nn) {
        float rn = rs[nn];
        if (rn == 0.f) continue;        // wave-uniform: prefix-mask rows skip
        uint4 v = *(const uint4*)(Eg + (size_t)(r0 + nn) * NCODES + col0);
        unsigned int u[4] = {v.x, v.y, v.z, v.w};
#pragma unroll
        for (int q = 0; q < 4; ++q) {
            acc[2 * q]     += rn * __builtin_bit_cast(float, u[q] << 16);
            acc[2 * q + 1] += rn * __builtin_bit_cast(float, u[q] & 0xffff0000u);
        }
    }
    float* outp = cdp + (size_t)(blockIdx.y & (NSLICE - 1)) * NCODES;
#pragma unroll
    for (int t = 0; t < 8; ++t) atomicAdd(&outp[col0 + t], acc[t]);
}

// ---------------- fallback (small ws): two-pass GEMM (writes cdp slice 0) -------
template <int PASS>
__global__ __launch_bounds__(256, 2) void k_gemm(
    const unsigned short* __restrict__ zbf, const unsigned short* __restrict__ cbbf,
    const float* __restrict__ z2, const float* __restrict__ c2,
    const int* __restrict__ lengths, const int* __restrict__ stride_p,
    float* __restrict__ Sg, float* __restrict__ cd) {
    __shared__ unsigned short As[128 * 64];
    __shared__ unsigned short Bs[128 * 64];
    __shared__ float z2s[128], c2s[128], rs[128];
    __shared__ int s_any;
    int tid = threadIdx.x;
    int r0 = blockIdx.y * 128, c0 = blockIdx.x * 128;
    if (tid == 0) s_any = 0;
    __syncthreads();
    if (tid < 128) {
        int n = r0 + tid;
        int valid = 0;
        if (n < NROWS) {
            int b = n / TT, t = n - b * TT;
            int stride = stride_p[0];
            int nv = lengths[b] / stride;
            if (nv > TT) nv = TT;
            valid = (t < nv);
        }
        if (valid) atomicOr(&s_any, 1);
        z2s[tid] = z2[r0 + tid];
        c2s[tid] = c2[c0 + tid];
        if (PASS == 2) rs[tid] = valid ? (1.0f / Sg[r0 + tid]) : 0.0f;
    }
    __syncthreads();
    if (!s_any) return;

    int wave = tid >> 6, lane = tid & 63;
    int l15 = lane & 15, l4 = lane >> 4;
    int wr = (wave >> 1) * 64, wc = (wave & 1) * 64;
    int srow = lane >> 3;
    int scg = (lane & 7) ^ srow;
    const unsigned short* ag = zbf + (size_t)(r0 + wave * 32 + srow) * DIM + scg * 8;
    const unsigned short* bg = cbbf + (size_t)(c0 + wave * 32 + srow) * DIM + scg * 8;
    unsigned short* al = As + (wave * 32) * 64;
    unsigned short* bl = Bs + (wave * 32) * 64;

    floatx4 acc[4][4];
    const floatx4 zero = {0.f, 0.f, 0.f, 0.f};
#pragma unroll
    for (int i = 0; i < 4; ++i)
#pragma unroll
        for (int j = 0; j < 4; ++j) acc[i][j] = zero;
    int sw = l15 & 7;
    for (int kc = 0; kc < 8; ++kc) {
#pragma unroll
        for (int q = 0; q < 4; ++q) {
            glds16(ag + (size_t)q * 8 * DIM + kc * 64, al + q * 8 * 64);
            glds16(bg + (size_t)q * 8 * DIM + kc * 64, bl + q * 8 * 64);
        }
        __syncthreads();
#pragma unroll
        for (int ks = 0; ks < 64; ks += 32) {
            int g = (ks >> 3) + l4;
            int pcg = g ^ sw;
            bf16x8 av[4], bv[4];
#pragma unroll
            for (int i = 0; i < 4; ++i)
                av[i] = __builtin_bit_cast(bf16x8, *(const ushortx8*)&As[(wr + 16 * i + l15) * 64 + pcg * 8]);
#pragma unroll
            for (int j = 0; j < 4; ++j)
                bv[j] = __builtin_bit_cast(bf16x8, *(const ushortx8*)&Bs[(wc + 16 * j + l15) * 64 + pcg * 8]);
#pragma unroll
            for (int i = 0; i < 4; ++i)
#pragma unroll
                for (int j = 0; j < 4; ++j)
                    acc[i][j] = __builtin_amdgcn_mfma_f32_16x16x32_bf16(av[i], bv[j], acc[i][j], 0, 0, 0);
        }
        __syncthreads();
    }
    if (PASS == 1) {
#pragma unroll
        for (int i = 0; i < 4; ++i) {
#pragma unroll
            for (int r = 0; r < 4; ++r) {
                int rl = wr + 16 * i + 4 * l4 + r;
                float z2v = z2s[rl];
                float s = 0.f;
#pragma unroll
                for (int j = 0; j < 4; ++j) {
                    int cl = wc + 16 * j + l15;
                    float d2 = z2v + c2s[cl] - 2.0f * acc[i][j][r];
                    float d = sqrtf(fmaxf(d2, 1e-12f));
                    s += __expf(SHIFTC - d);
                }
                s += __shfl_xor(s, 1); s += __shfl_xor(s, 2);
                s += __shfl_xor(s, 4); s += __shfl_xor(s, 8);
                if (l15 == 0) atomicAdd(&Sg[r0 + rl], s);
            }
        }
    } else {
#pragma unroll
        for (int j = 0; j < 4; ++j) {
            int cl = wc + 16 * j + l15;
            float c2v = c2s[cl];
            float cs = 0.f;
#pragma unroll
            for (int i = 0; i < 4; ++i) {
#pragma unroll
                for (int r = 0; r < 4; ++r) {
                    int rl = wr + 16 * i + 4 * l4 + r;
                    float d2 = z2s[rl] + c2v - 2.0f * acc[i][j][r];
                    float d = sqrtf(fmaxf(d2, 1e-12f));
                    cs += __expf(SHIFTC - d) * rs[rl];
                }
            }
            cs += __shfl_xor(cs, 16); cs += __shfl_xor(cs, 32);
            if (l4 == 0) atomicAdd(&cd[c0 + cl], cs);
        }
    }
}

// ---------------- finalize: reduce slices, normalize, entropy (1024 thr) --------
__global__ __launch_bounds__(1024) void k_final(const float* __restrict__ cdp,
                                                float* __restrict__ out) {
    __shared__ float red[16];
    __shared__ float tot_s;
    int tid = threadIdx.x, lane = tid & 63, wave = tid >> 6;
    float vloc[4];
    float t = 0.f;
#pragma unroll
    for (int q = 0; q < 4; ++q) {
        int i = tid + q * 1024;
        float v = 0.f;
#pragma unroll
        for (int s = 0; s < NSLICE; ++s) v += cdp[(size_t)s * NCODES + i];
        vloc[q] = v;
        t += v;
    }
#pragma unroll
    for (int off = 32; off >= 1; off >>= 1) t += __shfl_down(t, off);
    if (lane == 0) red[wave] = t;
    __syncthreads();
    if (tid == 0) {
        float tt = 0.f;
#pragma unroll
        for (int w = 0; w < 16; ++w) tt += red[w];
        tot_s = tt;
    }
    __syncthreads();
    float inv = 1.0f / (tot_s + 1e-8f);
    float e = 0.f;
#pragma unroll
    for (int q = 0; q < 4; ++q) {
        float p = vloc[q] * inv;
        e += p * __logf(p + 1e-8f);
    }
#pragma unroll
    for (int off = 32; off >= 1; off >>= 1) e += __shfl_down(e, off);
    if (lane == 0) red[wave] = e;
    __syncthreads();
    if (tid == 0) {
        float ee = 0.f;
#pragma unroll
        for (int w = 0; w < 16; ++w) ee += red[w];
        out[0] = 1.0f - (-ee) / __logf((float)NCODES);
    }
}

// ---------------- launcher ----------------
extern "C" void kernel_launch(void* const* d_in, const int* in_sizes, int n_in,
                              void* d_out, int out_size, void* d_ws, size_t ws_size,
                              hipStream_t stream) {
    const float* sf = (const float*)d_in[0];
    const float* cb = (const float*)d_in[1];
    const int* lengths = (const int*)d_in[2];
    const int* stride_p = (const int*)d_in[3];

    float* wsf = (float*)d_ws;
    float* Sg = wsf;                                     // NROWS_PAD
    float* cdp = Sg + NROWS_PAD;                         // NSLICE*NCODES
    const size_t OFF_Z2 = NZERO;
    const size_t OFF_C2 = OFF_Z2 + NROWS_PAD;
    const size_t OFF_ZB = (OFF_C2 + NCODES + 3) & ~(size_t)3;  // 16B-align bf16 region
    float* z2 = wsf + OFF_Z2;
    float* c2 = wsf + OFF_C2;
    unsigned short* zbf = (unsigned short*)(wsf + OFF_ZB);     // NROWS_PAD*DIM bf16
    unsigned short* cbbf = zbf + (size_t)NROWS_PAD * DIM;      // NCODES*DIM bf16
    unsigned short* Eg = cbbf + (size_t)NCODES * DIM;          // NROWS_PAD*NCODES bf16

    size_t need = OFF_ZB * 4
                + ((size_t)NROWS_PAD * DIM + (size_t)NCODES * DIM
                 + (size_t)NROWS_PAD * NCODES) * 2;

    k_prep<<<dim3(TBLKS + CBLKS), 256, 0, stream>>>(sf, cb, zbf, cbbf, z2, c2, Sg);
    if (ws_size >= need) {
        k_gemm1<<<dim3(NBLKX, ROW_TILES), 256, 0, stream>>>(
            zbf, cbbf, z2, c2, lengths, stride_p, Sg, Eg);
        k_scan<<<dim3(2, NROWS_PAD / 32), 256, 0, stream>>>(
            Eg, Sg, lengths, stride_p, cdp);
    } else {
        k_gemm<1><<<dim3(NBLKX, ROW_TILES), 256, 0, stream>>>(zbf, cbbf, z2, c2, lengths, stride_p, Sg, cdp);
        k_gemm<2><<<dim3(NBLKX, ROW_TILES), 256, 0, stream>>>(zbf, cbbf, z2, c2, lengths, stride_p, Sg, cdp);
    }
    k_final<<<1, 1024, 0, stream>>>(cdp, (float*)d_out);
}